// Round 4
// baseline (515.398 us; speedup 1.0000x reference)
//
#include <hip/hip_runtime.h>

// Two-phase nnz-centric CSR SpMV.
// Reference semantics (JAX searchsorted): row 0 sums j in [0, off[1]);
// row r>=1 sums j in [off[r], off[r+1]); j >= off[num_rows] dropped.
//
// Phase 1: prod[j] = vals[j] * x[col[j]]  -- perfectly coalesced streams +
//          independent gathers (4 per thread in flight), no divergence.
// Phase 2: out[r] = sum prod[off[r]..off[r+1])  -- single load stream,
//          16 lanes/row, shuffle reduce.

typedef int   vint4   __attribute__((ext_vector_type(4)));
typedef float vfloat4 __attribute__((ext_vector_type(4)));

__global__ void spmv_prod(const float* __restrict__ vals,
                          const float* __restrict__ x,
                          const int*   __restrict__ col,
                          float*       __restrict__ prod,
                          int nnz) {
    const int t = blockIdx.x * blockDim.x + threadIdx.x;
    int j = t * 4;
    if (j + 3 < nnz) {
        // Non-temporal on the streaming arrays: don't evict x (4 MB) from L2.
        vint4   c = __builtin_nontemporal_load((const vint4*)(col + j));
        vfloat4 v = __builtin_nontemporal_load((const vfloat4*)(vals + j));
        vfloat4 p;
        p.x = v.x * x[c.x];
        p.y = v.y * x[c.y];
        p.z = v.z * x[c.z];
        p.w = v.w * x[c.w];
        __builtin_nontemporal_store(p, (vfloat4*)(prod + j));
    } else {
        for (; j < nnz; ++j) prod[j] = vals[j] * x[col[j]];
    }
}

#define L2R 16  // lanes per row in phase 2

__global__ void spmv_rowsum(const float* __restrict__ prod,
                            const int*   __restrict__ off,
                            float*       __restrict__ out,
                            int num_rows) {
    const int tid  = blockIdx.x * blockDim.x + threadIdx.x;
    const int r    = tid / L2R;
    const int lane = tid & (L2R - 1);
    if (r >= num_rows) return;

    const int start = (r == 0) ? 0 : off[r];
    const int end   = off[r + 1];

    float s = 0.0f;
    for (int j = start + lane; j < end; j += L2R)
        s += __builtin_nontemporal_load(prod + j);

    s += __shfl_xor(s, 1);
    s += __shfl_xor(s, 2);
    s += __shfl_xor(s, 4);
    s += __shfl_xor(s, 8);

    if (lane == 0) out[r] = s;
}

// ---- fallback (round-1 kernel) if ws is too small for prod ----
#define FB_LANES 8
__global__ void spmv_csr_vector(const float* __restrict__ vals,
                                const float* __restrict__ x,
                                const int*   __restrict__ col,
                                const int*   __restrict__ off,
                                float*       __restrict__ out,
                                int num_rows) {
    const int tid     = blockIdx.x * blockDim.x + threadIdx.x;
    const int group   = tid / FB_LANES;
    const int lane    = tid & (FB_LANES - 1);
    const int ngroups = (gridDim.x * blockDim.x) / FB_LANES;
    for (int r = group; r < num_rows; r += ngroups) {
        const int start = (r == 0) ? 0 : off[r];
        const int end   = off[r + 1];
        float sum = 0.0f;
        for (int j = start + lane; j < end; j += FB_LANES)
            sum += vals[j] * x[col[j]];
        sum += __shfl_xor(sum, 1);
        sum += __shfl_xor(sum, 2);
        sum += __shfl_xor(sum, 4);
        if (lane == 0) out[r] = sum;
    }
}

extern "C" void kernel_launch(void* const* d_in, const int* in_sizes, int n_in,
                              void* d_out, int out_size, void* d_ws, size_t ws_size,
                              hipStream_t stream) {
    const float* vals = (const float*)d_in[0];
    const float* x    = (const float*)d_in[1];
    const int*   col  = (const int*)d_in[2];
    const int*   off  = (const int*)d_in[3];
    float*       out  = (float*)d_out;

    const int nnz      = in_sizes[0];
    const int num_rows = in_sizes[3] - 1;
    const int block    = 256;

    if (ws_size >= (size_t)nnz * sizeof(float)) {
        float* prod = (float*)d_ws;
        int grid1 = (nnz / 4 + block - 1) / block + 1;  // +1 covers the tail thread
        spmv_prod<<<grid1, block, 0, stream>>>(vals, x, col, prod, nnz);

        long long t2 = (long long)num_rows * L2R;
        int grid2 = (int)((t2 + block - 1) / block);
        spmv_rowsum<<<grid2, block, 0, stream>>>(prod, off, out, num_rows);
    } else {
        long long t = (long long)num_rows * FB_LANES;
        int grid = (int)((t + block - 1) / block);
        spmv_csr_vector<<<grid, block, 0, stream>>>(vals, x, col, off, out, num_rows);
    }
}